// Round 1
// baseline (659.234 us; speedup 1.0000x reference)
//
#include <hip/hip_runtime.h>
#include <hip/hip_bf16.h>
#include <math.h>

// Shapes (compile-time)
// N=1, D=17, Dp=16, S=128, H=2048, NH=16, HD=128, K=16, Sk=128

typedef __attribute__((ext_vector_type(8))) short bf16x8;
typedef __attribute__((ext_vector_type(4))) short bf16x4;
typedef __attribute__((ext_vector_type(4))) float f32x4;

__device__ __forceinline__ unsigned short f2bf(float f) {
    union { float f; unsigned u; } c; c.f = f;
    unsigned u = c.u + 0x7FFF + ((c.u >> 16) & 1);   // RNE
    return (unsigned short)(u >> 16);
}

// ---------------- RMSNorm (rows 128..2175 of hidden_states) -> bf16 xn (2048x2048)
__global__ __launch_bounds__(256) void rms_kernel(const float* __restrict__ hs,
                                                  const float* __restrict__ rw,
                                                  unsigned short* __restrict__ xn) {
    int row = blockIdx.x;                       // 0..2047  (global row = row+128)
    const float* x = hs + (size_t)(row + 128) * 2048;
    int tid = threadIdx.x;
    float4 a = ((const float4*)x)[tid * 2];
    float4 b = ((const float4*)x)[tid * 2 + 1];
    float ss = a.x*a.x + a.y*a.y + a.z*a.z + a.w*a.w
             + b.x*b.x + b.y*b.y + b.z*b.z + b.w*b.w;
#pragma unroll
    for (int m = 1; m < 64; m <<= 1) ss += __shfl_xor(ss, m);
    __shared__ float part[4];
    if ((tid & 63) == 0) part[tid >> 6] = ss;
    __syncthreads();
    float tot = part[0] + part[1] + part[2] + part[3];
    float rstd = rsqrtf(tot * (1.0f / 2048.0f) + 1e-6f);
    float4 wa = ((const float4*)rw)[tid * 2];
    float4 wb = ((const float4*)rw)[tid * 2 + 1];
    bf16x8 o;
    o[0] = (short)f2bf(a.x * rstd * wa.x);
    o[1] = (short)f2bf(a.y * rstd * wa.y);
    o[2] = (short)f2bf(a.z * rstd * wa.z);
    o[3] = (short)f2bf(a.w * rstd * wa.w);
    o[4] = (short)f2bf(b.x * rstd * wb.x);
    o[5] = (short)f2bf(b.y * rstd * wb.y);
    o[6] = (short)f2bf(b.z * rstd * wb.z);
    o[7] = (short)f2bf(b.w * rstd * wb.w);
    *reinterpret_cast<bf16x8*>(&xn[(size_t)row * 2048 + tid * 8]) = o;
}

// ---------------- fp32 -> bf16 elementwise cast (4M elems)
__global__ __launch_bounds__(256) void cast_kernel(const float* __restrict__ in,
                                                   unsigned short* __restrict__ out) {
    size_t i = ((size_t)blockIdx.x * 256 + threadIdx.x) * 8;
    float4 a = *reinterpret_cast<const float4*>(in + i);
    float4 b = *reinterpret_cast<const float4*>(in + i + 4);
    bf16x8 o;
    o[0] = (short)f2bf(a.x); o[1] = (short)f2bf(a.y);
    o[2] = (short)f2bf(a.z); o[3] = (short)f2bf(a.w);
    o[4] = (short)f2bf(b.x); o[5] = (short)f2bf(b.y);
    o[6] = (short)f2bf(b.z); o[7] = (short)f2bf(b.w);
    *reinterpret_cast<bf16x8*>(out + i) = o;
}

// ---------------- C(2048x2048) = A(2048xK) * B(2048xK)^T, bf16 in, fp32 acc.
// 128x128 tile, BK=64, 4 waves (2x2), wave tile 64x64. Padded LDS stride 72.
template<int OUT_BF16>
__global__ __launch_bounds__(256) void gemm_bt(const unsigned short* __restrict__ A,
                                               const unsigned short* __restrict__ B,
                                               unsigned short* __restrict__ Cb,
                                               float* __restrict__ Cf) {
    __shared__ short As[128 * 72];
    __shared__ short Bs[128 * 72];
    int bm = (blockIdx.x >> 4) * 128;
    int bn = (blockIdx.x & 15) * 128;
    int tid = threadIdx.x;
    int lane = tid & 63, wid = tid >> 6;
    int wm = (wid >> 1) * 64, wn = (wid & 1) * 64;
    int r16 = lane & 15, g = lane >> 4;
    f32x4 acc[4][4] = {};

    for (int kt = 0; kt < 2048; kt += 64) {
#pragma unroll
        for (int p = 0; p < 4; ++p) {
            int idx = tid + p * 256;
            int r = idx >> 3, c = (idx & 7) * 8;
            *reinterpret_cast<bf16x8*>(&As[r * 72 + c]) =
                *reinterpret_cast<const bf16x8*>(&A[(size_t)(bm + r) * 2048 + kt + c]);
            *reinterpret_cast<bf16x8*>(&Bs[r * 72 + c]) =
                *reinterpret_cast<const bf16x8*>(&B[(size_t)(bn + r) * 2048 + kt + c]);
        }
        __syncthreads();
#pragma unroll
        for (int ks = 0; ks < 2; ++ks) {
            bf16x8 af[4], bfr[4];
#pragma unroll
            for (int i = 0; i < 4; ++i) {
                af[i]  = *reinterpret_cast<const bf16x8*>(&As[(wm + i * 16 + r16) * 72 + ks * 32 + g * 8]);
                bfr[i] = *reinterpret_cast<const bf16x8*>(&Bs[(wn + i * 16 + r16) * 72 + ks * 32 + g * 8]);
            }
#pragma unroll
            for (int i = 0; i < 4; ++i)
#pragma unroll
                for (int j = 0; j < 4; ++j)
                    acc[i][j] = __builtin_amdgcn_mfma_f32_16x16x32_bf16(af[i], bfr[j], acc[i][j], 0, 0, 0);
        }
        __syncthreads();
    }
#pragma unroll
    for (int i = 0; i < 4; ++i) {
        int row0 = bm + wm + i * 16 + g * 4;
#pragma unroll
        for (int j = 0; j < 4; ++j) {
            int col = bn + wn + j * 16 + r16;
#pragma unroll
            for (int rr = 0; rr < 4; ++rr) {
                float v = acc[i][j][rr];
                if (OUT_BF16) Cb[(size_t)(row0 + rr) * 2048 + col] = f2bf(v);
                else          Cf[(size_t)(row0 + rr) * 2048 + col] = v;
            }
        }
    }
}

// ---------------- Attention: grid 256 = (dp 0..15) x (h 0..15), 512 threads (8 waves).
// Per block: Q tile 128x128 (regs), loop k=0..15: stage K + V^T -> LDS bf16,
// QK^T MFMA, register softmax (16-lane shfl reduce), P*w -> LDS, PV MFMA accumulate.
__global__ __launch_bounds__(512) void attn_kernel(const unsigned short* __restrict__ q2d,
                                                   const float* __restrict__ ck,
                                                   const float* __restrict__ cv,
                                                   const float* __restrict__ wts,
                                                   unsigned short* __restrict__ o2d) {
    int dp = blockIdx.x >> 4;
    int h  = blockIdx.x & 15;
    int tid = threadIdx.x;
    int lane = tid & 63, w = tid >> 6;
    int r16 = lane & 15, g = lane >> 4;

    __shared__ short kbuf[128 * 136];   // K[t][hd]
    __shared__ short vtbuf[128 * 136];  // V^T[hd][t]
    __shared__ short pbuf[128 * 136];   // P[s][t]

    // Q fragments: wave w owns rows w*16..w*16+15; A-frag row = lane&15, k = (lane>>4)*8
    bf16x8 qf[4];
    {
        const unsigned short* qrow = q2d + (size_t)(dp * 128 + w * 16 + r16) * 2048 + h * 128 + g * 8;
#pragma unroll
        for (int ks = 0; ks < 4; ++ks)
            qf[ks] = *reinterpret_cast<const bf16x8*>(qrow + ks * 32);
    }
    f32x4 oacc[8] = {};
    const float sc = 0.088388347648318447f * 1.44269504088896f;  // 1/sqrt(128) * log2(e)

    for (int k = 0; k < 16; ++k) {
        size_t cbase = (size_t)(dp * 16 + k) * 128 * 2048 + h * 128;
        // stage K: [t][hd] bf16, stride 136
#pragma unroll
        for (int p = 0; p < 8; ++p) {
            int t = p * 16 + (tid >> 5);
            int hd0 = (tid & 31) * 4;
            float4 v = *reinterpret_cast<const float4*>(&ck[cbase + (size_t)t * 2048 + hd0]);
            bf16x4 s4;
            s4[0] = (short)f2bf(v.x); s4[1] = (short)f2bf(v.y);
            s4[2] = (short)f2bf(v.z); s4[3] = (short)f2bf(v.w);
            *reinterpret_cast<bf16x4*>(&kbuf[t * 136 + hd0]) = s4;
        }
        // stage V^T: [hd][t] bf16, stride 136 (transpose in registers, b128 writes)
        {
            int hd = tid & 127;
            int tg = tid >> 7;
#pragma unroll
            for (int p = 0; p < 4; ++p) {
                int t0 = p * 32 + tg * 8;
                bf16x8 s8;
#pragma unroll
                for (int j = 0; j < 8; ++j)
                    s8[j] = (short)f2bf(cv[cbase + (size_t)(t0 + j) * 2048 + hd]);
                *reinterpret_cast<bf16x8*>(&vtbuf[hd * 136 + t0]) = s8;
            }
        }
        __syncthreads();

        // QK^T: sacc[nb] covers cols nb*16+(lane&15), rows w*16 + g*4 + r
        f32x4 sacc[8] = {};
#pragma unroll
        for (int ks = 0; ks < 4; ++ks) {
#pragma unroll
            for (int nb = 0; nb < 8; ++nb) {
                bf16x8 kf = *reinterpret_cast<const bf16x8*>(&kbuf[(nb * 16 + r16) * 136 + ks * 32 + g * 8]);
                sacc[nb] = __builtin_amdgcn_mfma_f32_16x16x32_bf16(qf[ks], kf, sacc[nb], 0, 0, 0);
            }
        }

        // register softmax over t (cols), fold in chunk weight
        float wdk = wts[dp * 16 + k];
        float fac[4];
#pragma unroll
        for (int r = 0; r < 4; ++r) {
            float m = sacc[0][r];
#pragma unroll
            for (int nb = 1; nb < 8; ++nb) m = fmaxf(m, sacc[nb][r]);
            m = fmaxf(m, __shfl_xor(m, 1));
            m = fmaxf(m, __shfl_xor(m, 2));
            m = fmaxf(m, __shfl_xor(m, 4));
            m = fmaxf(m, __shfl_xor(m, 8));
            float s = 0.f;
#pragma unroll
            for (int nb = 0; nb < 8; ++nb) {
                float p = exp2f((sacc[nb][r] - m) * sc);
                sacc[nb][r] = p;
                s += p;
            }
            s += __shfl_xor(s, 1);
            s += __shfl_xor(s, 2);
            s += __shfl_xor(s, 4);
            s += __shfl_xor(s, 8);
            fac[r] = wdk / s;
        }
        // write P (each wave writes only its own 16 rows; consumed by same wave)
#pragma unroll
        for (int r = 0; r < 4; ++r)
#pragma unroll
            for (int nb = 0; nb < 8; ++nb)
                pbuf[(w * 16 + g * 4 + r) * 136 + nb * 16 + r16] = (short)f2bf(sacc[nb][r] * fac[r]);

        // PV: O[s][hd] += sum_t P[s][t] * V^T[hd][t]
#pragma unroll
        for (int ks = 0; ks < 4; ++ks) {
            bf16x8 pf = *reinterpret_cast<const bf16x8*>(&pbuf[(w * 16 + r16) * 136 + ks * 32 + g * 8]);
#pragma unroll
            for (int nb = 0; nb < 8; ++nb) {
                bf16x8 vf = *reinterpret_cast<const bf16x8*>(&vtbuf[(nb * 16 + r16) * 136 + ks * 32 + g * 8]);
                oacc[nb] = __builtin_amdgcn_mfma_f32_16x16x32_bf16(pf, vf, oacc[nb], 0, 0, 0);
            }
        }
        __syncthreads();   // all waves done with kbuf/vtbuf before next stage
    }

    // epilogue: o2d[dp*128 + s][h*128 + hd] bf16
#pragma unroll
    for (int nb = 0; nb < 8; ++nb) {
#pragma unroll
        for (int rr = 0; rr < 4; ++rr) {
            int row = dp * 128 + w * 16 + g * 4 + rr;
            int col = h * 128 + nb * 16 + r16;
            o2d[(size_t)row * 2048 + col] = f2bf(oacc[nb][rr]);
        }
    }
}

extern "C" void kernel_launch(void* const* d_in, const int* in_sizes, int n_in,
                              void* d_out, int out_size, void* d_ws, size_t ws_size,
                              hipStream_t stream) {
    const float* hs  = (const float*)d_in[0];
    const float* ck  = (const float*)d_in[1];
    const float* cv  = (const float*)d_in[2];
    const float* wts = (const float*)d_in[3];
    const float* rw  = (const float*)d_in[4];
    const float* Wq  = (const float*)d_in[5];
    const float* Wo  = (const float*)d_in[6];
    float* out = (float*)d_out;

    char* ws = (char*)d_ws;
    unsigned short* xn  = (unsigned short*)(ws);               // 8MB (reused as o2d)
    unsigned short* wqb = (unsigned short*)(ws + (8u  << 20)); // 8MB (reused as Wo bf16)
    unsigned short* qb  = (unsigned short*)(ws + (16u << 20)); // 8MB
    unsigned short* o2d = xn;
    unsigned short* wob = wqb;

    // zero the first S rows of the output (re-poisoned before every call)
    hipMemsetAsync(out, 0, (size_t)128 * 2048 * 4, stream);

    cast_kernel<<<2048, 256, 0, stream>>>(Wq, wqb);
    rms_kernel<<<2048, 256, 0, stream>>>(hs, rw, xn);
    gemm_bt<1><<<256, 256, 0, stream>>>(xn, wqb, qb, nullptr);          // Q = xn * Wq^T
    attn_kernel<<<256, 512, 0, stream>>>(qb, ck, cv, wts, o2d);
    cast_kernel<<<2048, 256, 0, stream>>>(Wo, wob);
    gemm_bt<0><<<256, 256, 0, stream>>>(o2d, wob, nullptr, out + (size_t)128 * 2048); // O = o2d * Wo^T
}